// Round 8
// baseline (5596.553 us; speedup 1.0000x reference)
//
#include <hip/hip_runtime.h>
#include <stdint.h>

#define Bb   16
#define INn  8192
#define Cc   64
#define Aa   512
#define Nn   512
#define OUTo 1024
#define Tt   32

// ---------------------------------------------------------------------------
// Spike schedule per (b, i) as a 32-bit mask (bit t = spike at cycle t).
// ---------------------------------------------------------------------------
__global__ void spike_kernel(const float* __restrict__ x,
                             uint32_t* __restrict__ spk) {
    int idx = blockIdx.x * 256 + threadIdx.x;
    if (idx >= Bb * INn) return;
    float xv = x[idx];
    float nf = rintf(xv * 32.0f);
    int nspk = (int)nf;
    uint32_t m;
    if (nspk >= 32) {
        m = 0xFFFFFFFFu;
    } else if (nspk <= 0) {
        m = 0u;
    } else {
        float spacing = 32.0f / nf;
        m = 0u;
        #pragma unroll
        for (int t = 0; t < 32; ++t) {
            float ct = (float)t;
            bool fire = (floorf(ct / spacing) < nf) &&
                        (floorf(fmodf(ct, spacing)) == 0.0f);
            if (fire) m |= (1u << t);
        }
    }
    spk[idx] = m;
}

// ---------------------------------------------------------------------------
// Persistent kernel. 256 blocks (1/CU via 160 KiB LDS) x 512 threads.
// Block = (c = blk>>2, n-tile nt = blk&3). Thread = (n = nt*128 + (tid&127),
// b-quad bq = tid>>7). W row for n: a<200 in 50 NAMED float4 registers
// (macro-generated scalars -> cannot go to scratch), a>=200 in LDS with
// XOR-swizzled slots (phys = q ^ ((row>>1)&7), stride 80 float4) ->
// conflict-free ds_read_b128 (2 dwords/bank per 16-lane phase).
// memb + fire-words in registers for all 32 cycles.
// Per cycle: gather own core's signals -> sync -> 512-step ascending fmaf
// chain per (b,n) [bit-identical to rounds 1-5] -> fire -> atomicExch buf
// words (device scope = coherence point) -> grid barrier (slot counter +
// __threadfence release/acquire). Reader at cycle t masks bit t-1, identical
// in pre/post-exch word versions -> benign race.  [proven correct in R7]
// ---------------------------------------------------------------------------
#define FMA16(w4, s0, s1, s2, s3)                                      \
    a0 = fmaf((w4).x, (s0).x, a0); a1 = fmaf((w4).x, (s0).y, a1);      \
    a2 = fmaf((w4).x, (s0).z, a2); a3 = fmaf((w4).x, (s0).w, a3);      \
    a0 = fmaf((w4).y, (s1).x, a0); a1 = fmaf((w4).y, (s1).y, a1);      \
    a2 = fmaf((w4).y, (s1).z, a2); a3 = fmaf((w4).y, (s1).w, a3);      \
    a0 = fmaf((w4).z, (s2).x, a0); a1 = fmaf((w4).z, (s2).y, a1);      \
    a2 = fmaf((w4).z, (s2).z, a2); a3 = fmaf((w4).z, (s2).w, a3);      \
    a0 = fmaf((w4).w, (s3).x, a0); a1 = fmaf((w4).w, (s3).y, a1);      \
    a2 = fmaf((w4).w, (s3).z, a2); a3 = fmaf((w4).w, (s3).w, a3);

#define REP50(M) M(0) M(1) M(2) M(3) M(4) M(5) M(6) M(7) M(8) M(9)    \
    M(10) M(11) M(12) M(13) M(14) M(15) M(16) M(17) M(18) M(19)        \
    M(20) M(21) M(22) M(23) M(24) M(25) M(26) M(27) M(28) M(29)        \
    M(30) M(31) M(32) M(33) M(34) M(35) M(36) M(37) M(38) M(39)        \
    M(40) M(41) M(42) M(43) M(44) M(45) M(46) M(47) M(48) M(49)

#define WDECL(k) float4 wg##k;
#define WLOAD(k) wg##k = myrow[k];
#define WSTEP(k) {                                                     \
    const float* s_ = sp + (size_t)(64 * (k));                         \
    float4 s0 = *(const float4*)(s_);                                  \
    float4 s1 = *(const float4*)(s_ + 16);                             \
    float4 s2 = *(const float4*)(s_ + 32);                             \
    float4 s3 = *(const float4*)(s_ + 48);                             \
    FMA16(wg##k, s0, s1, s2, s3) }

__global__ __launch_bounds__(512, 1) void persist_kernel(
        const float* __restrict__ W,
        const float* __restrict__ thr,
        const int* __restrict__ src_core,
        const int* __restrict__ src_index,
        const uint32_t* __restrict__ spk,
        uint32_t* __restrict__ buf,
        float* __restrict__ sigws,
        uint32_t* __restrict__ bar) {
    __shared__ float4 smem4[10240];            // 163840 B = 160 KiB exactly

    const int tid = threadIdx.x;
    const int c   = blockIdx.x >> 2;
    const int nt  = blockIdx.x & 3;
    const int nl  = tid & 127;                 // n within tile (= row)
    const int bq  = tid >> 7;                  // 0..3 -> b = bq*4 .. bq*4+3
    const int n   = nt * 128 + nl;

    const float* const wsrc = W + ((size_t)c * Nn + nt * 128) * Aa;

    // ---- Prologue B: W[a<200] -> 50 named float4 regs via LDS bounce ----
    {
        float4* st = smem4;                    // staging [128][50] float4
        for (int i = tid; i < 128 * 50; i += 512) {
            int r = i / 50, q = i - r * 50;
            st[i] = *(const float4*)(wsrc + (size_t)r * Aa + 4 * q);
        }
    }
    __syncthreads();
    REP50(WDECL)
    {
        const float4* myrow = smem4 + nl * 50;
        REP50(WLOAD)
    }
    __syncthreads();
    // ---- Prologue A: W[a>=200] -> swizzled LDS [128 rows][80 slots] ----
    for (int i = tid; i < 128 * 78; i += 512) {
        int r = i / 78, q = i - r * 78;
        float4 v = *(const float4*)(wsrc + (size_t)r * Aa + 200 + 4 * q);
        smem4[r * 80 + (q ^ ((r >> 1) & 7))] = v;
    }
    __syncthreads();

    float    mb0 = 0.f, mb1 = 0.f, mb2 = 0.f, mb3 = 0.f;   // memb (regs)
    uint32_t bw0 = 0u,  bw1 = 0u,  bw2 = 0u,  bw3 = 0u;    // fire words
    float* const sig = sigws + (size_t)blockIdx.x * (Aa * Bb);
    const float th = thr[c];
    const int cbase = c * Aa;
    const int sx = (nl >> 1) & 7;              // LDS swizzle key
    const float4* const wbase = smem4 + nl * 80;

    for (int t = 0; t < Tt; ++t) {
        // ---- gather this core's full signal set (block-private) ----
        #pragma unroll 4
        for (int i = tid; i < Aa * Bb; i += 512) {
            int a = i >> 4, b = i & 15;
            int sc = src_core[cbase + a];
            int si = src_index[cbase + a];
            float v;
            if (sc < 0) {
                v = (float)((spk[b * INn + si] >> t) & 1u);
            } else if (t > 0) {
                v = (float)((buf[((sc << 4) + b) * Nn + si] >> (t - 1)) & 1u);
            } else {
                v = 0.0f;
            }
            sig[i] = v;
        }
        __syncthreads();

        // ---- dot: strictly ascending a, one chain per (b,n) ----
        float a0 = 0.f, a1 = 0.f, a2 = 0.f, a3 = 0.f;
        const float* sp = sig + bq * 4;
        REP50(WSTEP)                            // a = 0 .. 199 (registers)
        {
            const float* sp2 = sp + (size_t)200 * 16;
            #pragma unroll 2
            for (int q = 0; q < 78; ++q) {     // a = 200 .. 511 (LDS)
                float4 w4 = wbase[q ^ sx];
                const float* s_ = sp2 + (size_t)q * 64;
                float4 s0 = *(const float4*)(s_);
                float4 s1 = *(const float4*)(s_ + 16);
                float4 s2 = *(const float4*)(s_ + 32);
                float4 s3 = *(const float4*)(s_ + 48);
                FMA16(w4, s0, s1, s2, s3)
            }
        }

        // ---- memb update + fire (exactly as validated rounds) ----
        mb0 += a0; if (th < mb0) { mb0 -= th; bw0 |= 1u << t; }
        mb1 += a1; if (th < mb1) { mb1 -= th; bw1 |= 1u << t; }
        mb2 += a2; if (th < mb2) { mb2 -= th; bw2 |= 1u << t; }
        mb3 += a3; if (th < mb3) { mb3 -= th; bw3 |= 1u << t; }
        uint32_t* bp = buf + ((size_t)(c * Bb + bq * 4) * Nn) + n;
        atomicExch(&bp[0],      bw0);          // device-scope -> coherent
        atomicExch(&bp[Nn],     bw1);
        atomicExch(&bp[2 * Nn], bw2);
        atomicExch(&bp[3 * Nn], bw3);

        // ---- grid barrier (except after last cycle) ----
        if (t < Tt - 1) {
            __syncthreads();                   // all exchs of block complete
            if (tid == 0) {
                __threadfence();               // release
                atomicAdd(&bar[t], 1u);
                while (atomicAdd(&bar[t], 0u) < 256u) {
                    __builtin_amdgcn_s_sleep(2);
                }
                __threadfence();               // acquire
            }
            __syncthreads();
        }
    }
}

// ---------------------------------------------------------------------------
// Fallback path (round-2, known-correct) if ws is too small.
// ---------------------------------------------------------------------------
__global__ void gather_kernel(const int* __restrict__ src_core,
                              const int* __restrict__ src_index,
                              const uint32_t* __restrict__ spk,
                              const uint32_t* __restrict__ buf,
                              float* __restrict__ sig, int t) {
    int idx = blockIdx.x * 256 + threadIdx.x;
    int b  = idx & 15;
    int ca = idx >> 4;
    int sc = src_core[ca];
    int si = src_index[ca];
    float v;
    if (sc < 0) {
        v = (float)((spk[b * INn + si] >> t) & 1u);
    } else {
        v = (t > 0) ? (float)((buf[(sc * Bb + b) * Nn + si] >> (t - 1)) & 1u)
                    : 0.0f;
    }
    sig[ca * 16 + b] = v;
}

__global__ __launch_bounds__(128) void cycle_kernel_fb(
        const float* __restrict__ W,
        const float* __restrict__ thr,
        const float* __restrict__ sig,
        uint32_t* __restrict__ buf,
        float* __restrict__ memb,
        int t) {
    const int c  = blockIdx.x;
    const int bh = __builtin_amdgcn_readfirstlane(threadIdx.x >> 6);
    const int n  = blockIdx.y * 64 + (threadIdx.x & 63);

    const float* __restrict__ wrow = W + (size_t)(c * Nn + n) * Aa;
    const float* __restrict__ sgc  = sig + c * Aa * 16 + bh * 8;

    float acc[8];
    #pragma unroll
    for (int j = 0; j < 8; ++j) acc[j] = 0.0f;

    for (int a0 = 0; a0 < Aa; a0 += 4) {
        float4 w4 = *(const float4*)(wrow + a0);
        #pragma unroll
        for (int k = 0; k < 4; ++k) {
            float w = (k == 0) ? w4.x : (k == 1) ? w4.y : (k == 2) ? w4.z : w4.w;
            const float* sa = sgc + (size_t)(a0 + k) * 16;
            #pragma unroll
            for (int j = 0; j < 8; ++j) acc[j] += w * sa[j];
        }
    }

    const float th = thr[c];
    #pragma unroll
    for (int j = 0; j < 8; ++j) {
        int b = bh * 8 + j;
        size_t off = (size_t)(c * Bb + b) * Nn + n;
        float m = memb[off] + acc[j];
        uint32_t wd = buf[off];
        if (th < m) { m -= th; wd |= (1u << t); }
        memb[off] = m;
        buf[off] = wd;
    }
}

// ---------------------------------------------------------------------------
// out[b, o] = popcount(buf[oc[o], b, oi[o]]).
// ---------------------------------------------------------------------------
__global__ void out_kernel(const uint32_t* __restrict__ buf,
                           const int* __restrict__ oc,
                           const int* __restrict__ oi,
                           float* __restrict__ out) {
    int idx = blockIdx.x * 256 + threadIdx.x;
    if (idx >= Bb * OUTo) return;
    int b = idx / OUTo;
    int o = idx - b * OUTo;
    uint32_t wd = buf[(oc[o] * Bb + b) * Nn + oi[o]];
    out[idx] = (float)__popc(wd);
}

extern "C" void kernel_launch(void* const* d_in, const int* in_sizes, int n_in,
                              void* d_out, int out_size, void* d_ws,
                              size_t ws_size, hipStream_t stream) {
    const float* x         = (const float*)d_in[0];
    const float* W         = (const float*)d_in[1];
    const float* thr       = (const float*)d_in[2];
    const int*   src_core  = (const int*)d_in[3];
    const int*   src_index = (const int*)d_in[4];
    const int*   osc       = (const int*)d_in[5];
    const int*   osi       = (const int*)d_in[6];
    float* out = (float*)d_out;

    // ws layout: buf | bar | spk | memb(fb) | sig(fb) | sigws(persist)
    char* p = (char*)d_ws;
    uint32_t* buf   = (uint32_t*)p;  p += (size_t)Cc * Bb * Nn * 4;   // 2 MB
    uint32_t* bar   = (uint32_t*)p;  p += 256;
    uint32_t* spk   = (uint32_t*)p;  p += (size_t)Bb * INn * 4;       // 512 KB
    float*    membf = (float*)p;     p += (size_t)Cc * Bb * Nn * 4;   // 2 MB (fb)
    float*    sigf  = (float*)p;     p += (size_t)Cc * Aa * Bb * 4;   // 2 MB (fb)
    float*    sigws = (float*)p;     p += (size_t)256 * Aa * Bb * 4;  // 8 MB
    const bool use_persist = ((size_t)(p - (char*)d_ws) <= ws_size);

    spike_kernel<<<dim3((Bb * INn) / 256), 256, 0, stream>>>(x, spk);

    if (use_persist) {
        // zero buf + bar (contiguous); sigws needs no init
        (void)hipMemsetAsync(buf, 0, (size_t)Cc * Bb * Nn * 4 + 256, stream);
        persist_kernel<<<dim3(256), 512, 0, stream>>>(
            W, thr, src_core, src_index, spk, buf, sigws, bar);
    } else {
        (void)hipMemsetAsync(buf, 0, (size_t)Cc * Bb * Nn * 4, stream);
        (void)hipMemsetAsync(membf, 0, (size_t)Cc * Bb * Nn * 4, stream);
        for (int t = 0; t < Tt; ++t) {
            gather_kernel<<<dim3((Cc * Aa * Bb) / 256), 256, 0, stream>>>(
                src_core, src_index, spk, buf, sigf, t);
            cycle_kernel_fb<<<dim3(Cc, 8), 128, 0, stream>>>(
                W, thr, sigf, buf, membf, t);
        }
    }

    out_kernel<<<dim3((Bb * OUTo + 255) / 256), 256, 0, stream>>>(
        buf, osc, osi, out);
}

// Round 9
// 3899.639 us; speedup vs baseline: 1.4351x; 1.4351x over previous
//
#include <hip/hip_runtime.h>
#include <stdint.h>

#define Bb   16
#define INn  8192
#define Cc   64
#define Aa   512
#define Nn   512
#define OUTo 1024
#define Tt   32

// ---------------------------------------------------------------------------
// Spike schedule per (b, i) as a 32-bit mask (bit t = spike at cycle t).
// ---------------------------------------------------------------------------
__global__ void spike_kernel(const float* __restrict__ x,
                             uint32_t* __restrict__ spk) {
    int idx = blockIdx.x * 256 + threadIdx.x;
    if (idx >= Bb * INn) return;
    float xv = x[idx];
    float nf = rintf(xv * 32.0f);
    int nspk = (int)nf;
    uint32_t m;
    if (nspk >= 32) {
        m = 0xFFFFFFFFu;
    } else if (nspk <= 0) {
        m = 0u;
    } else {
        float spacing = 32.0f / nf;
        m = 0u;
        #pragma unroll
        for (int t = 0; t < 32; ++t) {
            float ct = (float)t;
            bool fire = (floorf(ct / spacing) < nf) &&
                        (floorf(fmodf(ct, spacing)) == 0.0f);
            if (fire) m |= (1u << t);
        }
    }
    spk[idx] = m;
}

// ---------------------------------------------------------------------------
// Persistent kernel. 256 blocks (1/CU via ~158 KB LDS) x 256 threads
// (4 waves = 1 wave/EU; amdgpu_waves_per_eu(1) lifts the VGPR cap to 512
// -- R7/R8's 8-wave blocks were silently capped at 128 and spilled W).
// Block = (c = blk>>2, n-tile nt = blk&3, 128 n). Thread = (n, 8 b's).
// W row for n: a<200 in 50 NAMED float4 regs, a>=200 in LDS rows of 316
// dwords (28-bank natural stagger -> 2-way/free, measured 4e5 conflicts
// in R7). memb + fire-words in registers all 32 cycles.
// Per cycle: gather core's signals (block-private global, 0/1 f32) -> sync
// -> 512-step ascending fmaf chain per (b,n) [bit-identical to rounds 1-5]
// -> fire -> atomicExch buf words (device scope = coherence point) ->
// grid barrier (slot counter + __threadfence). Reader at cycle t masks
// bit t-1, identical pre/post-exch -> benign race. [proven correct R7/R8]
// ---------------------------------------------------------------------------
#define FMA8(wc, sl, sh)                                               \
    a0 = fmaf((wc), (sl).x, a0); a1 = fmaf((wc), (sl).y, a1);          \
    a2 = fmaf((wc), (sl).z, a2); a3 = fmaf((wc), (sl).w, a3);          \
    a4 = fmaf((wc), (sh).x, a4); a5 = fmaf((wc), (sh).y, a5);          \
    a6 = fmaf((wc), (sh).z, a6); a7 = fmaf((wc), (sh).w, a7);

#define REP50(M) M(0) M(1) M(2) M(3) M(4) M(5) M(6) M(7) M(8) M(9)    \
    M(10) M(11) M(12) M(13) M(14) M(15) M(16) M(17) M(18) M(19)        \
    M(20) M(21) M(22) M(23) M(24) M(25) M(26) M(27) M(28) M(29)        \
    M(30) M(31) M(32) M(33) M(34) M(35) M(36) M(37) M(38) M(39)        \
    M(40) M(41) M(42) M(43) M(44) M(45) M(46) M(47) M(48) M(49)

#define WDECL(k) float4 wg##k;
#define WLOAD(k) wg##k = myrow[k];
#define WSTEP(k) {                                                     \
    const float* b_ = sp + 64 * (k);                                   \
    float4 s0l = *(const float4*)(b_);                                 \
    float4 s0h = *(const float4*)(b_ + 4);                             \
    float4 s1l = *(const float4*)(b_ + 16);                            \
    float4 s1h = *(const float4*)(b_ + 20);                            \
    float4 s2l = *(const float4*)(b_ + 32);                            \
    float4 s2h = *(const float4*)(b_ + 36);                            \
    float4 s3l = *(const float4*)(b_ + 48);                            \
    float4 s3h = *(const float4*)(b_ + 52);                            \
    FMA8(wg##k.x, s0l, s0h)                                            \
    FMA8(wg##k.y, s1l, s1h)                                            \
    FMA8(wg##k.z, s2l, s2h)                                            \
    FMA8(wg##k.w, s3l, s3h) }

__global__ __launch_bounds__(256)
__attribute__((amdgpu_waves_per_eu(1)))
void persist_kernel(
        const float* __restrict__ W,
        const float* __restrict__ thr,
        const int* __restrict__ src_core,
        const int* __restrict__ src_index,
        const uint32_t* __restrict__ spk,
        uint32_t* __restrict__ buf,
        float* __restrict__ sigws,
        uint32_t* __restrict__ bar) {
    __shared__ float4 smem4[10112];            // 161792 B
    float* const wl = (float*)smem4;           // final: [128 rows][316 dw]

    const int tid  = threadIdx.x;
    const int c    = blockIdx.x >> 2;
    const int nt   = blockIdx.x & 3;
    const int nl   = tid & 127;                // n within tile (= row)
    const int boct = tid >> 7;                 // 0/1 -> b = boct*8 .. +7
    const int n    = nt * 128 + nl;

    const float* const wsrc = W + ((size_t)c * Nn + nt * 128) * Aa;

    // ---- Prologue B: W[a<200] -> 50 named float4 regs via LDS bounce ----
    {
        float4* st = smem4;                    // staging [128][50] float4
        for (int i = tid; i < 128 * 50; i += 256) {
            int r = i / 50, q = i - r * 50;
            st[i] = *(const float4*)(wsrc + (size_t)r * Aa + 4 * q);
        }
    }
    __syncthreads();
    REP50(WDECL)
    {
        const float4* myrow = smem4 + nl * 50;
        REP50(WLOAD)
    }
    __syncthreads();
    // ---- Prologue A: W[a>=200] -> LDS rows of 316 dwords ----
    for (int i = tid; i < 128 * 78; i += 256) {
        int r = i / 78, q = i - r * 78;
        float4 v = *(const float4*)(wsrc + (size_t)r * Aa + 200 + 4 * q);
        *(float4*)(wl + (size_t)r * 316 + 4 * q) = v;
    }
    __syncthreads();

    float    mb0 = 0.f, mb1 = 0.f, mb2 = 0.f, mb3 = 0.f;
    float    mb4 = 0.f, mb5 = 0.f, mb6 = 0.f, mb7 = 0.f;
    uint32_t bw0 = 0u, bw1 = 0u, bw2 = 0u, bw3 = 0u;
    uint32_t bw4 = 0u, bw5 = 0u, bw6 = 0u, bw7 = 0u;
    float* const sig = sigws + (size_t)blockIdx.x * (Aa * Bb);
    const float th = thr[c];
    const int cbase = c * Aa;
    const float* const wrow = wl + (size_t)nl * 316;

    for (int t = 0; t < Tt; ++t) {
        // ---- gather this core's full signal set (block-private) ----
        #pragma unroll 4
        for (int i = tid; i < Aa * Bb; i += 256) {
            int a = i >> 4, b = i & 15;
            int sc = src_core[cbase + a];
            int si = src_index[cbase + a];
            float v;
            if (sc < 0) {
                v = (float)((spk[b * INn + si] >> t) & 1u);
            } else if (t > 0) {
                v = (float)((buf[((sc << 4) + b) * Nn + si] >> (t - 1)) & 1u);
            } else {
                v = 0.0f;
            }
            sig[i] = v;
        }
        __syncthreads();

        // ---- dot: strictly ascending a, one chain per (b,n) ----
        float a0 = 0.f, a1 = 0.f, a2 = 0.f, a3 = 0.f;
        float a4 = 0.f, a5 = 0.f, a6 = 0.f, a7 = 0.f;
        const float* sp = sig + boct * 8;
        REP50(WSTEP)                            // a = 0 .. 199 (registers)
        {
            const float* sp2 = sp + 3200;       // a = 200 .. 511 (LDS W)
            #pragma unroll 2
            for (int q = 0; q < 78; ++q) {
                float4 w4 = *(const float4*)(wrow + 4 * q);
                const float* b_ = sp2 + 64 * q;
                float4 s0l = *(const float4*)(b_);
                float4 s0h = *(const float4*)(b_ + 4);
                float4 s1l = *(const float4*)(b_ + 16);
                float4 s1h = *(const float4*)(b_ + 20);
                float4 s2l = *(const float4*)(b_ + 32);
                float4 s2h = *(const float4*)(b_ + 36);
                float4 s3l = *(const float4*)(b_ + 48);
                float4 s3h = *(const float4*)(b_ + 52);
                FMA8(w4.x, s0l, s0h)
                FMA8(w4.y, s1l, s1h)
                FMA8(w4.z, s2l, s2h)
                FMA8(w4.w, s3l, s3h)
            }
        }

        // ---- memb update + fire (exactly as validated rounds) ----
        mb0 += a0; if (th < mb0) { mb0 -= th; bw0 |= 1u << t; }
        mb1 += a1; if (th < mb1) { mb1 -= th; bw1 |= 1u << t; }
        mb2 += a2; if (th < mb2) { mb2 -= th; bw2 |= 1u << t; }
        mb3 += a3; if (th < mb3) { mb3 -= th; bw3 |= 1u << t; }
        mb4 += a4; if (th < mb4) { mb4 -= th; bw4 |= 1u << t; }
        mb5 += a5; if (th < mb5) { mb5 -= th; bw5 |= 1u << t; }
        mb6 += a6; if (th < mb6) { mb6 -= th; bw6 |= 1u << t; }
        mb7 += a7; if (th < mb7) { mb7 -= th; bw7 |= 1u << t; }
        uint32_t* bp = buf + ((size_t)(c * Bb + boct * 8) * Nn) + n;
        atomicExch(&bp[0],      bw0);
        atomicExch(&bp[Nn],     bw1);
        atomicExch(&bp[2 * Nn], bw2);
        atomicExch(&bp[3 * Nn], bw3);
        atomicExch(&bp[4 * Nn], bw4);
        atomicExch(&bp[5 * Nn], bw5);
        atomicExch(&bp[6 * Nn], bw6);
        atomicExch(&bp[7 * Nn], bw7);

        // ---- grid barrier (except after last cycle) ----
        if (t < Tt - 1) {
            __syncthreads();
            if (tid == 0) {
                __threadfence();               // release
                atomicAdd(&bar[t], 1u);
                while (atomicAdd(&bar[t], 0u) < 256u) {
                    __builtin_amdgcn_s_sleep(2);
                }
                __threadfence();               // acquire
            }
            __syncthreads();
        }
    }
}

// ---------------------------------------------------------------------------
// Fallback path (round-2, known-correct) if ws is too small.
// ---------------------------------------------------------------------------
__global__ void gather_kernel(const int* __restrict__ src_core,
                              const int* __restrict__ src_index,
                              const uint32_t* __restrict__ spk,
                              const uint32_t* __restrict__ buf,
                              float* __restrict__ sig, int t) {
    int idx = blockIdx.x * 256 + threadIdx.x;
    int b  = idx & 15;
    int ca = idx >> 4;
    int sc = src_core[ca];
    int si = src_index[ca];
    float v;
    if (sc < 0) {
        v = (float)((spk[b * INn + si] >> t) & 1u);
    } else {
        v = (t > 0) ? (float)((buf[(sc * Bb + b) * Nn + si] >> (t - 1)) & 1u)
                    : 0.0f;
    }
    sig[ca * 16 + b] = v;
}

__global__ __launch_bounds__(128) void cycle_kernel_fb(
        const float* __restrict__ W,
        const float* __restrict__ thr,
        const float* __restrict__ sig,
        uint32_t* __restrict__ buf,
        float* __restrict__ memb,
        int t) {
    const int c  = blockIdx.x;
    const int bh = __builtin_amdgcn_readfirstlane(threadIdx.x >> 6);
    const int n  = blockIdx.y * 64 + (threadIdx.x & 63);

    const float* __restrict__ wrow = W + (size_t)(c * Nn + n) * Aa;
    const float* __restrict__ sgc  = sig + c * Aa * 16 + bh * 8;

    float acc[8];
    #pragma unroll
    for (int j = 0; j < 8; ++j) acc[j] = 0.0f;

    for (int a0 = 0; a0 < Aa; a0 += 4) {
        float4 w4 = *(const float4*)(wrow + a0);
        #pragma unroll
        for (int k = 0; k < 4; ++k) {
            float w = (k == 0) ? w4.x : (k == 1) ? w4.y : (k == 2) ? w4.z : w4.w;
            const float* sa = sgc + (size_t)(a0 + k) * 16;
            #pragma unroll
            for (int j = 0; j < 8; ++j) acc[j] += w * sa[j];
        }
    }

    const float th = thr[c];
    #pragma unroll
    for (int j = 0; j < 8; ++j) {
        int b = bh * 8 + j;
        size_t off = (size_t)(c * Bb + b) * Nn + n;
        float m = memb[off] + acc[j];
        uint32_t wd = buf[off];
        if (th < m) { m -= th; wd |= (1u << t); }
        memb[off] = m;
        buf[off] = wd;
    }
}

// ---------------------------------------------------------------------------
// out[b, o] = popcount(buf[oc[o], b, oi[o]]).
// ---------------------------------------------------------------------------
__global__ void out_kernel(const uint32_t* __restrict__ buf,
                           const int* __restrict__ oc,
                           const int* __restrict__ oi,
                           float* __restrict__ out) {
    int idx = blockIdx.x * 256 + threadIdx.x;
    if (idx >= Bb * OUTo) return;
    int b = idx / OUTo;
    int o = idx - b * OUTo;
    uint32_t wd = buf[(oc[o] * Bb + b) * Nn + oi[o]];
    out[idx] = (float)__popc(wd);
}

extern "C" void kernel_launch(void* const* d_in, const int* in_sizes, int n_in,
                              void* d_out, int out_size, void* d_ws,
                              size_t ws_size, hipStream_t stream) {
    const float* x         = (const float*)d_in[0];
    const float* W         = (const float*)d_in[1];
    const float* thr       = (const float*)d_in[2];
    const int*   src_core  = (const int*)d_in[3];
    const int*   src_index = (const int*)d_in[4];
    const int*   osc       = (const int*)d_in[5];
    const int*   osi       = (const int*)d_in[6];
    float* out = (float*)d_out;

    // ws layout: buf | bar | spk | memb(fb) | sig(fb) | sigws(persist)
    char* p = (char*)d_ws;
    uint32_t* buf   = (uint32_t*)p;  p += (size_t)Cc * Bb * Nn * 4;   // 2 MB
    uint32_t* bar   = (uint32_t*)p;  p += 256;
    uint32_t* spk   = (uint32_t*)p;  p += (size_t)Bb * INn * 4;       // 512 KB
    float*    membf = (float*)p;     p += (size_t)Cc * Bb * Nn * 4;   // 2 MB (fb)
    float*    sigf  = (float*)p;     p += (size_t)Cc * Aa * Bb * 4;   // 2 MB (fb)
    float*    sigws = (float*)p;     p += (size_t)256 * Aa * Bb * 4;  // 8 MB
    const bool use_persist = ((size_t)(p - (char*)d_ws) <= ws_size);

    spike_kernel<<<dim3((Bb * INn) / 256), 256, 0, stream>>>(x, spk);

    if (use_persist) {
        // zero buf + bar (contiguous); sigws needs no init
        (void)hipMemsetAsync(buf, 0, (size_t)Cc * Bb * Nn * 4 + 256, stream);
        persist_kernel<<<dim3(256), 256, 0, stream>>>(
            W, thr, src_core, src_index, spk, buf, sigws, bar);
    } else {
        (void)hipMemsetAsync(buf, 0, (size_t)Cc * Bb * Nn * 4, stream);
        (void)hipMemsetAsync(membf, 0, (size_t)Cc * Bb * Nn * 4, stream);
        for (int t = 0; t < Tt; ++t) {
            gather_kernel<<<dim3((Cc * Aa * Bb) / 256), 256, 0, stream>>>(
                src_core, src_index, spk, buf, sigf, t);
            cycle_kernel_fb<<<dim3(Cc, 8), 128, 0, stream>>>(
                W, thr, sigf, buf, membf, t);
        }
    }

    out_kernel<<<dim3((Bb * OUTo + 255) / 256), 256, 0, stream>>>(
        buf, osc, osi, out);
}